// Round 10
// baseline (55.993 us; speedup 1.0000x reference)
//
#include <hip/hip_runtime.h>
#include <hip/hip_bf16.h>
#include <math.h>

#define S_LEN   4096
#define HID     2048
#define NB      8
#define SC      64            // s-chunks: one block per 64 rows (R9 best)
#define S_PER   (S_LEN / SC)  // 64 rows per block
#define R       16            // TOTAL_RANK
#define AD      32            // ADAPT_DIM

typedef float f4 __attribute__((ext_vector_type(4)));

// ---------------- Kernel 1: fused mean-pool + W1 projection ----------------
// (byte-identical to R9's 54.5us version)
__global__ __launch_bounds__(512)
void pool_proj(const float* __restrict__ hs,
               const float* __restrict__ W1,
               float* __restrict__ xpart) {
    __shared__ float hsum[HID];        // 8 KB
    __shared__ float cpart[16][AD];    // 2 KB
    int t  = threadIdx.x;              // 0..511
    int sc = blockIdx.x;               // 0..63
    int b  = blockIdx.y;               // 0..7

    const float* base = hs + ((size_t)b * S_LEN + (size_t)sc * S_PER) * HID;
    const f4* p = (const f4*)(base + t * 4);     // cols [t*4 .. t*4+3]
    f4 acc = (f4)(0.f);
#pragma unroll 8
    for (int s = 0; s < S_PER; ++s)
        acc += __builtin_nontemporal_load(p + (size_t)s * (HID / 4));
    *(f4*)&hsum[t * 4] = acc;
    __syncthreads();

    // c[j] = sum_h hsum[h]*W1[h][j]; 16 groups of 32 lanes, group g owns
    // h in [g*128, g*128+128). W1 reads 128B-coalesced per group, L2-hot.
    int j = t & 31, g = t >> 5;
    const float* w = W1 + (size_t)(g * 128) * AD + j;
    float c = 0.f;
#pragma unroll 4
    for (int k = 0; k < 128; ++k)
        c += hsum[g * 128 + k] * w[(size_t)k * AD];
    cpart[g][j] = c;
    __syncthreads();

    if (t < AD) {
        float s = 0.f;
#pragma unroll
        for (int gg = 0; gg < 16; ++gg) s += cpart[gg][t];
        xpart[((size_t)(b * SC + sc)) * AD + t] = s;
    }
}

// ---- Kernel 2: hoisted-load tail — controller redo + masked FWHT ----
// 128 blocks x 256 threads, one row per thread (256 rows/block, 16 blocks
// per batch). ra loads ISSUE FIRST (T14 issue-early): their HBM latency
// hides under the xpart-reduce phase. Controller redundant per block
// (identical mask per batch); 1/32 folded into ms.
__global__ __launch_bounds__(256)
void ctrl_hadamard(const float* __restrict__ xpart,
                   const float* __restrict__ b1,
                   const float* __restrict__ gamma,
                   const float* __restrict__ beta,
                   const float* __restrict__ W2,
                   const float* __restrict__ b2v,
                   const float* __restrict__ mlog,
                   const float* __restrict__ rsc,
                   const float* __restrict__ ra,
                   float* __restrict__ out) {
    __shared__ float xp[8][AD];
    __shared__ float xv[AD];
    __shared__ float xg[AD];
    __shared__ float comb[R];
    __shared__ float ms[R];
    int t   = threadIdx.x;            // 0..255
    int blk = blockIdx.x;             // 0..127
    int b   = blk >> 4;               // 16 blocks per batch

    // --- issue ra loads FIRST; latency hides under the controller ---
    size_t row = (size_t)blk * 256 + t;
    const f4* src = (const f4*)(ra + row * R);
    f4 r0 = __builtin_nontemporal_load(src + 0);
    f4 r1 = __builtin_nontemporal_load(src + 1);
    f4 r2 = __builtin_nontemporal_load(src + 2);
    f4 r3 = __builtin_nontemporal_load(src + 3);

    // --- controller (redundant per block, identical across a batch) ---
    int j = t & 31, g = t >> 5;       // 8 groups of 32
    const float* xb = xpart + (size_t)b * SC * AD;
    float s = 0.f;
#pragma unroll 8
    for (int r = 0; r < SC / 8; ++r)          // 8 rows per group
        s += xb[(size_t)(g * (SC / 8) + r) * AD + j];
    xp[g][j] = s;
    __syncthreads();

    if (t < AD) {
        float x = 0.f;
#pragma unroll
        for (int gg = 0; gg < 8; ++gg) x += xp[gg][t];
        xv[t] = x * (1.0f / (float)S_LEN) + b1[t];
    }
    __syncthreads();

    if (t < AD) {
        float mu = 0.f;
#pragma unroll
        for (int k = 0; k < AD; ++k) mu += xv[k];
        mu *= (1.0f / AD);
        float var = 0.f;
#pragma unroll
        for (int k = 0; k < AD; ++k) { float d = xv[k] - mu; var += d * d; }
        var *= (1.0f / AD);
        float x = (xv[t] - mu) * rsqrtf(var + 1e-5f) * gamma[t] + beta[t];
        xg[t] = 0.5f * x * (1.0f + erff(x * 0.70710678118654752f));  // exact GELU
    }
    __syncthreads();

    if (t < R) {
        float lg = b2v[t];
#pragma unroll
        for (int k = 0; k < AD; ++k) lg += xg[k] * W2[(size_t)k * R + t];
        comb[t] = lg + mlog[t];
    }
    __syncthreads();

    if (t < R) {
        float v = comb[t];
        int cnt = 0;
#pragma unroll
        for (int k = 0; k < R; ++k)
            cnt += (comb[k] > v) || (comb[k] == v && k < t);
        ms[t] = (cnt < 8) ? rsc[t] * 0.03125f : 0.f;   // fold 1/32
    }
    __syncthreads();

    // --- masked scale + FWHT-16 (one row per thread) ---
    float a[R];
    a[0]  = r0.x; a[1]  = r0.y; a[2]  = r0.z; a[3]  = r0.w;
    a[4]  = r1.x; a[5]  = r1.y; a[6]  = r1.z; a[7]  = r1.w;
    a[8]  = r2.x; a[9]  = r2.y; a[10] = r2.z; a[11] = r2.w;
    a[12] = r3.x; a[13] = r3.y; a[14] = r3.z; a[15] = r3.w;
#pragma unroll
    for (int r = 0; r < R; ++r) a[r] *= ms[r];

    // FWHT-16 (Sylvester); 1/32 already folded into ms
#pragma unroll
    for (int hstep = 1; hstep < R; hstep <<= 1) {
#pragma unroll
        for (int i = 0; i < R; ++i) {
            if ((i & hstep) == 0) {
                float u = a[i], v = a[i | hstep];
                a[i] = u + v; a[i | hstep] = u - v;
            }
        }
    }

    f4* dst = (f4*)(out + row * R);
#pragma unroll
    for (int i = 0; i < 4; ++i) {
        f4 v;
        v.x = a[4 * i + 0]; v.y = a[4 * i + 1];
        v.z = a[4 * i + 2]; v.w = a[4 * i + 3];
        __builtin_nontemporal_store(v, dst + i);
    }
}

extern "C" void kernel_launch(void* const* d_in, const int* in_sizes, int n_in,
                              void* d_out, int out_size, void* d_ws, size_t ws_size,
                              hipStream_t stream) {
    const float* hs    = (const float*)d_in[0];  // (8,4096,2048)
    const float* ra    = (const float*)d_in[1];  // (8,4096,16)
    const float* W1    = (const float*)d_in[2];  // (2048,32)
    const float* b1    = (const float*)d_in[3];  // (32)
    const float* gamma = (const float*)d_in[4];  // (32)
    const float* beta  = (const float*)d_in[5];  // (32)
    const float* W2    = (const float*)d_in[6];  // (32,16)
    const float* b2v   = (const float*)d_in[7];  // (16)
    const float* mlog  = (const float*)d_in[8];  // (16)
    const float* rsc   = (const float*)d_in[9];  // (16)
    float* out = (float*)d_out;

    float* xpart = (float*)d_ws;                 // 512*32 f32 = 64 KB

    pool_proj    <<<dim3(SC, NB), 512, 0, stream>>>(hs, W1, xpart);
    ctrl_hadamard<<<128, 256, 0, stream>>>(xpart, b1, gamma, beta,
                                           W2, b2v, mlog, rsc, ra, out);
}

// Round 11
// 54.085 us; speedup vs baseline: 1.0353x; 1.0353x over previous
//
#include <hip/hip_runtime.h>
#include <hip/hip_bf16.h>
#include <math.h>

#define S_LEN   4096
#define HID     2048
#define NB      8
#define SC      64            // s-chunks: one block per 64 rows
#define S_PER   (S_LEN / SC)  // 64 rows per block
#define R       16            // TOTAL_RANK
#define AD      32            // ADAPT_DIM

typedef float f4 __attribute__((ext_vector_type(4)));

// ---------------- Kernel 1: fused mean-pool + W1 projection ----------------
// grid (64 sc, 8 b) = 512 blocks x 1024 threads -> 2 blocks/CU x 16 waves
// = 32 waves/CU (MAX occupancy; R9 had 16). Same block count as R9 => same
// W1 L2 traffic and same number of projection tails. Each thread streams 32
// rows of one f4 column-half; halves merged in LDS.
__global__ __launch_bounds__(1024)
void pool_proj(const float* __restrict__ hs,
               const float* __restrict__ W1,
               float* __restrict__ xpart) {
    __shared__ float phsum[2][HID];    // 16 KB
    __shared__ float cpart[32][AD];    // 4 KB
    int t   = threadIdx.x;             // 0..1023
    int col = t & 511;                 // f4 column (0..511)
    int hr  = t >> 9;                  // row-half (0 or 1)
    int sc  = blockIdx.x;              // 0..63
    int b   = blockIdx.y;              // 0..7

    const float* base = hs +
        ((size_t)b * S_LEN + (size_t)sc * S_PER + (size_t)hr * (S_PER / 2)) * HID;
    const f4* p = (const f4*)(base + col * 4);
    f4 acc = (f4)(0.f);
#pragma unroll 8
    for (int s = 0; s < S_PER / 2; ++s)         // 32 rows per thread
        acc += __builtin_nontemporal_load(p + (size_t)s * (HID / 4));
    *(f4*)&phsum[hr][col * 4] = acc;
    __syncthreads();

    // merge the two row-halves: 1024 threads cover 2048 floats (2 each)
    {
        float v0 = phsum[0][t]        + phsum[1][t];
        float v1 = phsum[0][t + 1024] + phsum[1][t + 1024];
        __syncthreads();
        phsum[0][t]        = v0;
        phsum[0][t + 1024] = v1;
    }
    __syncthreads();

    // c[j] = sum_h hsum[h]*W1[h][j]; 32 groups of 32 lanes, group g owns
    // h in [g*64, g*64+64). W1 reads 128B-coalesced per group, L2-hot.
    int j = t & 31, g = t >> 5;
    const float* w = W1 + (size_t)(g * 64) * AD + j;
    float c = 0.f;
#pragma unroll 4
    for (int k = 0; k < 64; ++k)
        c += phsum[0][g * 64 + k] * w[(size_t)k * AD];
    cpart[g][j] = c;
    __syncthreads();

    if (t < AD) {
        float s = 0.f;
#pragma unroll
        for (int gg = 0; gg < 32; ++gg) s += cpart[gg][t];
        xpart[((size_t)(b * SC + sc)) * AD + t] = s;
    }
}

// ---- Kernel 2: per-block controller redo + masked FWHT (R9 verbatim) ----
// grid 256, block 128 -> one row per thread, 128 rows per block, 32 blocks
// per batch. Every block redundantly recomputes the tiny controller for its
// batch from xpart (8 KB, L2-hot) -> deterministic identical mask; then
// streams its 128 rows of rank_activations through the masked FWHT-16.
__global__ void ctrl_hadamard(const float* __restrict__ xpart,
                              const float* __restrict__ b1,
                              const float* __restrict__ gamma,
                              const float* __restrict__ beta,
                              const float* __restrict__ W2,
                              const float* __restrict__ b2v,
                              const float* __restrict__ mlog,
                              const float* __restrict__ rsc,
                              const float* __restrict__ ra,
                              float* __restrict__ out) {
    __shared__ float xp[4][AD];
    __shared__ float xv[AD];
    __shared__ float xg[AD];
    __shared__ float comb[R];
    __shared__ float ms[R];
    int t   = threadIdx.x;            // 0..127
    int blk = blockIdx.x;             // 0..255
    int b   = blk >> 5;               // 32 blocks per batch

    // --- controller (redundant per block, identical across a batch) ---
    int j = t & 31, g = t >> 5;       // 4 groups of 32
    const float* xb = xpart + (size_t)b * SC * AD;
    float s = 0.f;
#pragma unroll 8
    for (int r = 0; r < SC / 4; ++r)          // 16 rows per group
        s += xb[(size_t)(g * (SC / 4) + r) * AD + j];
    xp[g][j] = s;
    __syncthreads();

    if (t < AD) {
        float x = 0.f;
#pragma unroll
        for (int gg = 0; gg < 4; ++gg) x += xp[gg][t];
        xv[t] = x * (1.0f / (float)S_LEN) + b1[t];
    }
    __syncthreads();

    if (t < AD) {
        float mu = 0.f;
#pragma unroll
        for (int k = 0; k < AD; ++k) mu += xv[k];
        mu *= (1.0f / AD);
        float var = 0.f;
#pragma unroll
        for (int k = 0; k < AD; ++k) { float d = xv[k] - mu; var += d * d; }
        var *= (1.0f / AD);
        float x = (xv[t] - mu) * rsqrtf(var + 1e-5f) * gamma[t] + beta[t];
        xg[t] = 0.5f * x * (1.0f + erff(x * 0.70710678118654752f));  // exact GELU
    }
    __syncthreads();

    if (t < R) {
        float lg = b2v[t];
#pragma unroll
        for (int k = 0; k < AD; ++k) lg += xg[k] * W2[(size_t)k * R + t];
        comb[t] = lg + mlog[t];
    }
    __syncthreads();

    if (t < R) {
        float v = comb[t];
        int cnt = 0;
#pragma unroll
        for (int k = 0; k < R; ++k)
            cnt += (comb[k] > v) || (comb[k] == v && k < t);
        ms[t] = (cnt < 8) ? rsc[t] : 0.f;
    }
    __syncthreads();

    // --- masked scale + FWHT-16 (one row per thread) ---
    size_t row = (size_t)blk * 128 + t;
    const f4* src = (const f4*)(ra + row * R);
    float a[R];
#pragma unroll
    for (int i = 0; i < 4; ++i) {
        f4 v = __builtin_nontemporal_load(src + i);
        a[4 * i + 0] = v.x; a[4 * i + 1] = v.y;
        a[4 * i + 2] = v.z; a[4 * i + 3] = v.w;
    }
#pragma unroll
    for (int r = 0; r < R; ++r) a[r] *= ms[r];

    // FWHT-16 (Sylvester ordering); recursive /sqrt(n) => total 1/32
#pragma unroll
    for (int hstep = 1; hstep < R; hstep <<= 1) {
#pragma unroll
        for (int i = 0; i < R; ++i) {
            if ((i & hstep) == 0) {
                float u = a[i], v = a[i | hstep];
                a[i] = u + v; a[i | hstep] = u - v;
            }
        }
    }

    f4* dst = (f4*)(out + row * R);
#pragma unroll
    for (int i = 0; i < 4; ++i) {
        f4 v;
        v.x = a[4 * i + 0] * 0.03125f; v.y = a[4 * i + 1] * 0.03125f;
        v.z = a[4 * i + 2] * 0.03125f; v.w = a[4 * i + 3] * 0.03125f;
        __builtin_nontemporal_store(v, dst + i);
    }
}

extern "C" void kernel_launch(void* const* d_in, const int* in_sizes, int n_in,
                              void* d_out, int out_size, void* d_ws, size_t ws_size,
                              hipStream_t stream) {
    const float* hs    = (const float*)d_in[0];  // (8,4096,2048)
    const float* ra    = (const float*)d_in[1];  // (8,4096,16)
    const float* W1    = (const float*)d_in[2];  // (2048,32)
    const float* b1    = (const float*)d_in[3];  // (32)
    const float* gamma = (const float*)d_in[4];  // (32)
    const float* beta  = (const float*)d_in[5];  // (32)
    const float* W2    = (const float*)d_in[6];  // (32,16)
    const float* b2v   = (const float*)d_in[7];  // (16)
    const float* mlog  = (const float*)d_in[8];  // (16)
    const float* rsc   = (const float*)d_in[9];  // (16)
    float* out = (float*)d_out;

    float* xpart = (float*)d_ws;                 // 512*32 f32 = 64 KB

    pool_proj    <<<dim3(SC, NB), 1024, 0, stream>>>(hs, W1, xpart);
    ctrl_hadamard<<<256, 128, 0, stream>>>(xpart, b1, gamma, beta,
                                           W2, b2v, mlog, rsc, ra, out);
}